// Round 1
// baseline (132.041 us; speedup 1.0000x reference)
//
#include <hip/hip_runtime.h>
#include <hip/hip_bf16.h>
#include <math.h>

#define B_ROWS 4096
#define D_DIM 512
#define TWO_B 8192
#define HW_N 256
#define BASE_T 0.07f
#define ALPHA_C 0.5f
#define LOG2E 1.44269504088896340736f

typedef float v4f __attribute__((ext_vector_type(4)));

__device__ __forceinline__ float fast_exp2(float x) {
#if __has_builtin(__builtin_amdgcn_exp2f)
    return __builtin_amdgcn_exp2f(x);
#else
    return exp2f(x);
#endif
}

// ---------------------------------------------------------------------------
// Kernel 1: normalize, temps, pos_sim; write X as packed fp8 e4m3 (OCP).
// One block (256 thr) per sample row b; thread t handles dims 2t, 2t+1.
// ---------------------------------------------------------------------------
__global__ __launch_bounds__(256) void prep_kernel(
    const float* __restrict__ emb1, const float* __restrict__ emb2,
    const float* __restrict__ att, unsigned short* __restrict__ X8,
    float* __restrict__ inv_temp, float* __restrict__ pos)
{
    const int b = blockIdx.x;
    const int t = threadIdx.x;
    const float2 a1 = ((const float2*)(emb1 + (size_t)b * D_DIM))[t];
    const float2 a2 = ((const float2*)(emb2 + (size_t)b * D_DIM))[t];
    float av = att[(size_t)b * HW_N + t];
    float s1  = a1.x * a1.x + a1.y * a1.y;
    float s2  = a2.x * a2.x + a2.y * a2.y;
    float s12 = a1.x * a2.x + a1.y * a2.y;
    #pragma unroll
    for (int m = 1; m < 64; m <<= 1) {
        s1  += __shfl_xor(s1, m, 64);
        s2  += __shfl_xor(s2, m, 64);
        s12 += __shfl_xor(s12, m, 64);
        av  += __shfl_xor(av, m, 64);
    }
    __shared__ float red[4][4];
    const int w = t >> 6, lane = t & 63;
    if (lane == 0) { red[w][0] = s1; red[w][1] = s2; red[w][2] = s12; red[w][3] = av; }
    __syncthreads();
    const float T1  = red[0][0] + red[1][0] + red[2][0] + red[3][0];
    const float T2  = red[0][1] + red[1][1] + red[2][1] + red[3][1];
    const float T12 = red[0][2] + red[1][2] + red[2][2] + red[3][2];
    const float Ta  = red[0][3] + red[1][3] + red[2][3] + red[3][3];
    const float i1 = 1.0f / fmaxf(sqrtf(T1), 1e-12f);
    const float i2 = 1.0f / fmaxf(sqrtf(T2), 1e-12f);
    const float it = 1.0f / (BASE_T * (1.0f + ALPHA_C * (Ta * (1.0f / 256.0f))));
    const int p1 = __builtin_amdgcn_cvt_pk_fp8_f32(a1.x * i1, a1.y * i1, 0, false);
    const int p2 = __builtin_amdgcn_cvt_pk_fp8_f32(a2.x * i2, a2.y * i2, 0, false);
    X8[(size_t)b * 256 + t]            = (unsigned short)(p1 & 0xffff);
    X8[(size_t)(b + B_ROWS) * 256 + t] = (unsigned short)(p2 & 0xffff);
    if (t == 0) {
        inv_temp[b] = it * LOG2E;
        inv_temp[b + B_ROWS] = it * LOG2E;
        pos[b] = (T12 * i1 * i2) * it;       // ln units, exact fp32
    }
}

// ---------------------------------------------------------------------------
// Kernel 2: triangular Gram (rb<=cb) in FP8 e4m3.
// R5 change: BK=128, 4 phases, DOUBLE-BUFFERED glds prefetch pipeline
// (T3-minimum recipe): stage(p+1, buf^1) issued BEFORE compute(p), ONE
// barrier per phase. vmcnt(0) drain at the barrier now lands after ~64
// MFMAs/wave instead of immediately after issue -> staging latency hidden.
// LDS total unchanged (64 KB -> still 2 blocks/CU).
// XOR swizzle re-derived for 8-unit rows: LDS[r][u] = global[r][u ^ (r&7)].
// ---------------------------------------------------------------------------
__device__ __forceinline__ void gload_lds16(const void* g, void* s) {
    __builtin_amdgcn_global_load_lds(
        (const __attribute__((address_space(1))) unsigned int*)g,
        (__attribute__((address_space(3))) unsigned int*)s,
        16, 0, 0);
}

__global__ __launch_bounds__(256) void gram_kernel(
    const unsigned char* __restrict__ X8,
    const float* __restrict__ inv_temp,
    float* __restrict__ partial)
{
    // --- XCD-contiguous remap: 2080 = 8 XCDs x 260 contiguous tri-ids ---
    const int bid = (blockIdx.x & 7) * 260 + (blockIdx.x >> 3);
    // --- triangular index: bid -> (rb, cb), rb <= cb ---
    int rb = (int)((129.0f - sqrtf(129.0f * 129.0f - 8.0f * (float)bid)) * 0.5f);
    rb = rb < 0 ? 0 : (rb > 63 ? 63 : rb);
    while (rb > 0 && (rb * (129 - rb)) / 2 > bid) rb--;
    while (rb < 63 && ((rb + 1) * (129 - (rb + 1))) / 2 <= bid) rb++;
    const int cb = rb + (bid - (rb * (129 - rb)) / 2);

    // double-buffered: 2 x 128 rows x 128 B = 2 x 16 KB per matrix
    __shared__ unsigned char smA[2][16384];
    __shared__ unsigned char smB[2][16384];

    const int rowBase = rb * 128;
    const int colBase = cb * 128;

    const int tid  = threadIdx.x;
    const int w    = tid >> 6;
    const int lane = tid & 63;
    const int quad = lane >> 4;
    const int t    = lane & 15;
    const int wm   = w >> 1;
    const int wn   = w & 1;

    // staging roles: each glds covers 8 rows x 8 units(16B) = 1 KB
    const int srow   = lane >> 3;   // 0..7 (row within group)
    const int schunk = lane & 7;    // 0..7 (16B unit within row)

    const unsigned char* Arow0 = X8 + (size_t)rowBase * D_DIM;
    const unsigned char* Brow0 = X8 + (size_t)colBase * D_DIM;

    v4f acc[4][4];
    #pragma unroll
    for (int a = 0; a < 4; a++)
        #pragma unroll
        for (int b2 = 0; b2 < 4; b2++)
            acc[a][b2] = v4f{0.0f, 0.0f, 0.0f, 0.0f};

    // ---- prologue: stage phase 0 into buffer 0 ----
    #pragma unroll
    for (int j = 0; j < 4; j++) {
        const int g = w * 4 + j;            // row group 0..15 (8 rows)
        const int r = g * 8 + srow;
        const int gc = schunk ^ (r & 7);    // XOR swizzle via global unit
        gload_lds16(Arow0 + (size_t)r * D_DIM + gc * 16, &smA[0][g * 1024]);
        gload_lds16(Brow0 + (size_t)r * D_DIM + gc * 16, &smB[0][g * 1024]);
    }
    __syncthreads();

    // ---- 4-phase double-buffered main loop ----
    #pragma unroll
    for (int p = 0; p < 4; p++) {
        const int cur = p & 1;
        const int nxt = cur ^ 1;

        // issue next-phase staging FIRST (hidden under this phase's MFMAs)
        if (p < 3) {
            const int kk = (p + 1) * 128;
            #pragma unroll
            for (int j = 0; j < 4; j++) {
                const int g = w * 4 + j;
                const int r = g * 8 + srow;
                const int gc = schunk ^ (r & 7);
                gload_lds16(Arow0 + (size_t)r * D_DIM + kk + gc * 16, &smA[nxt][g * 1024]);
                gload_lds16(Brow0 + (size_t)r * D_DIM + kk + gc * 16, &smB[nxt][g * 1024]);
            }
        }

        // compute current phase: 4 k-slices of 32 B
        #pragma unroll
        for (int s = 0; s < 4; s++) {
            // lane's k-chunk: global unit ug = s*2 + (quad>>1), half = quad&1
            // stored at LDS unit pu = ug ^ (row&7) = ug ^ (t&7)
            const int pu = (s * 2 + (quad >> 1)) ^ (t & 7);
            const int off = pu * 16 + (quad & 1) * 8;
            long aF[4], bF[4];
            #pragma unroll
            for (int mi = 0; mi < 4; mi++)
                aF[mi] = *(const long*)&smA[cur][(wm * 64 + mi * 16 + t) * 128 + off];
            #pragma unroll
            for (int ni = 0; ni < 4; ni++)
                bF[ni] = *(const long*)&smB[cur][(wn * 64 + ni * 16 + t) * 128 + off];
            #pragma unroll
            for (int mi = 0; mi < 4; mi++)
                #pragma unroll
                for (int ni = 0; ni < 4; ni++)
                    acc[mi][ni] = __builtin_amdgcn_mfma_f32_16x16x32_fp8_fp8(
                        aF[mi], bF[ni], acc[mi][ni], 0, 0, 0);
        }

        // one barrier per phase: drains stage(p+1) (vmcnt) after the MFMAs,
        // and protects buf[cur] before phase p+2 overwrites it.
        __syncthreads();
    }

    // ---- Epilogue 1: row sums (temp_i), slice 2*cb+wn ----
    v4f itv[4];
    #pragma unroll
    for (int mi = 0; mi < 4; mi++)
        itv[mi] = *(const v4f*)&inv_temp[rowBase + wm * 64 + mi * 16 + quad * 4];

    float* prow = partial + (size_t)(cb * 2 + wn) * TWO_B;
    #pragma unroll
    for (int mi = 0; mi < 4; mi++) {
        #pragma unroll
        for (int r = 0; r < 4; r++) {
            const int i = rowBase + wm * 64 + mi * 16 + quad * 4 + r;
            const float it = itv[mi][r];
            float s = 0.0f;
            #pragma unroll
            for (int ni = 0; ni < 4; ni++) {
                const int j = colBase + wn * 64 + ni * 16 + t;
                const float v = fast_exp2(acc[mi][ni][r] * it);
                s += (i == j) ? 0.0f : v;
            }
            s += __shfl_xor(s, 1, 64);
            s += __shfl_xor(s, 2, 64);
            s += __shfl_xor(s, 4, 64);
            s += __shfl_xor(s, 8, 64);
            if (t == 0) prow[i] = s;
        }
    }

    // ---- Epilogue 2 (off-diag): col sums (temp_j), slice 2*rb+wm ----
    if (rb != cb) {
        float itj[4];
        float cs[4] = {0.0f, 0.0f, 0.0f, 0.0f};
        #pragma unroll
        for (int ni = 0; ni < 4; ni++)
            itj[ni] = inv_temp[colBase + wn * 64 + ni * 16 + t];
        #pragma unroll
        for (int mi = 0; mi < 4; mi++)
            #pragma unroll
            for (int r = 0; r < 4; r++)
                #pragma unroll
                for (int ni = 0; ni < 4; ni++)
                    cs[ni] += fast_exp2(acc[mi][ni][r] * itj[ni]);
        float* pcol = partial + (size_t)(rb * 2 + wm) * TWO_B;
        #pragma unroll
        for (int ni = 0; ni < 4; ni++) {
            cs[ni] += __shfl_xor(cs[ni], 16, 64);
            cs[ni] += __shfl_xor(cs[ni], 32, 64);
            if (quad == 0) pcol[colBase + wn * 64 + ni * 16 + t] = cs[ni];
        }
    }
}

// ---------------------------------------------------------------------------
// Kernel 3a: denom = sum of 128 slices; loss_i = log(denom) - pos; block sums
// ---------------------------------------------------------------------------
__global__ __launch_bounds__(256) void finish1(
    const float* __restrict__ partial, const float* __restrict__ pos,
    float* __restrict__ blockSums)
{
    const int i = blockIdx.x * 256 + threadIdx.x;
    float d = 0.0f;
    #pragma unroll 8
    for (int s = 0; s < 128; s++) d += partial[(size_t)s * TWO_B + i];
    float li = logf(d) - pos[i & (B_ROWS - 1)];
    #pragma unroll
    for (int m = 1; m < 64; m <<= 1) li += __shfl_xor(li, m, 64);
    __shared__ float red[4];
    const int w = threadIdx.x >> 6, lane = threadIdx.x & 63;
    if (lane == 0) red[w] = li;
    __syncthreads();
    if (threadIdx.x == 0) blockSums[blockIdx.x] = red[0] + red[1] + red[2] + red[3];
}

__global__ void finish2(const float* __restrict__ blockSums, float* __restrict__ out)
{
    const int lane = threadIdx.x;
    float v = (lane < 32) ? blockSums[lane] : 0.0f;
    #pragma unroll
    for (int m = 1; m < 64; m <<= 1) v += __shfl_xor(v, m, 64);
    if (lane == 0) out[0] = v * (1.0f / 8192.0f);
}

// ---------------------------------------------------------------------------
extern "C" void kernel_launch(void* const* d_in, const int* in_sizes, int n_in,
                              void* d_out, int out_size, void* d_ws, size_t ws_size,
                              hipStream_t stream) {
    const float* emb1 = (const float*)d_in[0];
    const float* emb2 = (const float*)d_in[1];
    const float* att  = (const float*)d_in[2];
    float* out = (float*)d_out;

    char* ws = (char*)d_ws;
    // layout: X8 fp8 [8192*512] = 4,194,304 B
    //         inv_temp f32 [8192]      -> +32,768
    //         pos f32 [4096]           -> +16,384
    //         partial f32 [128*8192]   -> +4,194,304
    //         blockSums f32 [32]       -> +128
    unsigned short* X8 = (unsigned short*)ws;
    float* inv_temp    = (float*)(ws + 4194304);
    float* pos         = (float*)(ws + 4194304 + 32768);
    float* partial     = (float*)(ws + 4194304 + 32768 + 16384);
    float* blockSums   = (float*)(ws + 4194304 + 32768 + 16384 + 4194304);

    prep_kernel<<<B_ROWS, 256, 0, stream>>>(emb1, emb2, att, X8, inv_temp, pos);
    gram_kernel<<<2080, 256, 0, stream>>>((const unsigned char*)X8, inv_temp, partial);
    finish1<<<TWO_B / 256, 256, 0, stream>>>(partial, pos, blockSums);
    finish2<<<1, 64, 0, stream>>>(blockSums, out);
}

// Round 2
// 121.278 us; speedup vs baseline: 1.0888x; 1.0888x over previous
//
#include <hip/hip_runtime.h>
#include <hip/hip_bf16.h>
#include <math.h>

#define B_ROWS 4096
#define D_DIM 512
#define TWO_B 8192
#define HW_N 256
#define BASE_T 0.07f
#define ALPHA_C 0.5f
#define LOG2E 1.44269504088896340736f

typedef float v4f __attribute__((ext_vector_type(4)));

__device__ __forceinline__ float fast_exp2(float x) {
#if __has_builtin(__builtin_amdgcn_exp2f)
    return __builtin_amdgcn_exp2f(x);
#else
    return exp2f(x);
#endif
}

// ---------------------------------------------------------------------------
// Kernel 1: normalize, temps, pos_sim; write X as packed fp8 e4m3 (OCP).
// One block (256 thr) per sample row b; thread t handles dims 2t, 2t+1.
// ---------------------------------------------------------------------------
__global__ __launch_bounds__(256) void prep_kernel(
    const float* __restrict__ emb1, const float* __restrict__ emb2,
    const float* __restrict__ att, unsigned short* __restrict__ X8,
    float* __restrict__ inv_temp, float* __restrict__ pos)
{
    const int b = blockIdx.x;
    const int t = threadIdx.x;
    const float2 a1 = ((const float2*)(emb1 + (size_t)b * D_DIM))[t];
    const float2 a2 = ((const float2*)(emb2 + (size_t)b * D_DIM))[t];
    float av = att[(size_t)b * HW_N + t];
    float s1  = a1.x * a1.x + a1.y * a1.y;
    float s2  = a2.x * a2.x + a2.y * a2.y;
    float s12 = a1.x * a2.x + a1.y * a2.y;
    #pragma unroll
    for (int m = 1; m < 64; m <<= 1) {
        s1  += __shfl_xor(s1, m, 64);
        s2  += __shfl_xor(s2, m, 64);
        s12 += __shfl_xor(s12, m, 64);
        av  += __shfl_xor(av, m, 64);
    }
    __shared__ float red[4][4];
    const int w = t >> 6, lane = t & 63;
    if (lane == 0) { red[w][0] = s1; red[w][1] = s2; red[w][2] = s12; red[w][3] = av; }
    __syncthreads();
    const float T1  = red[0][0] + red[1][0] + red[2][0] + red[3][0];
    const float T2  = red[0][1] + red[1][1] + red[2][1] + red[3][1];
    const float T12 = red[0][2] + red[1][2] + red[2][2] + red[3][2];
    const float Ta  = red[0][3] + red[1][3] + red[2][3] + red[3][3];
    const float i1 = 1.0f / fmaxf(sqrtf(T1), 1e-12f);
    const float i2 = 1.0f / fmaxf(sqrtf(T2), 1e-12f);
    const float it = 1.0f / (BASE_T * (1.0f + ALPHA_C * (Ta * (1.0f / 256.0f))));
    const int p1 = __builtin_amdgcn_cvt_pk_fp8_f32(a1.x * i1, a1.y * i1, 0, false);
    const int p2 = __builtin_amdgcn_cvt_pk_fp8_f32(a2.x * i2, a2.y * i2, 0, false);
    X8[(size_t)b * 256 + t]            = (unsigned short)(p1 & 0xffff);
    X8[(size_t)(b + B_ROWS) * 256 + t] = (unsigned short)(p2 & 0xffff);
    if (t == 0) {
        inv_temp[b] = it * LOG2E;
        inv_temp[b + B_ROWS] = it * LOG2E;
        pos[b] = (T12 * i1 * i2) * it;       // ln units, exact fp32
    }
}

// ---------------------------------------------------------------------------
// Kernel 2: triangular Gram (rb<=cb) in FP8 e4m3.
// R6 change: occupancy fix. BK=64, double-buffered -> LDS 32 KB total
// (2buf x 2mat x 128x64B) -> 4 blocks/CU (16 waves/CU) vs previous 2.
// R5 counters showed the latency-bound signature (Occ 18.5%, Mfma 20%,
// VALU 23%, HBM 3.6%): 2 waves/SIMD cannot hide ds_read/MFMA/barrier
// latency. Same 128x128 tile, same 4-wave epilogue mapping.
// Swizzle for 4x16B units/row: LDS[r][u] = G[r][u ^ ((r>>1)&3)].
// ---------------------------------------------------------------------------
__device__ __forceinline__ void gload_lds16(const void* g, void* s) {
    __builtin_amdgcn_global_load_lds(
        (const __attribute__((address_space(1))) unsigned int*)g,
        (__attribute__((address_space(3))) unsigned int*)s,
        16, 0, 0);
}

__global__ __launch_bounds__(256, 4) void gram_kernel(
    const unsigned char* __restrict__ X8,
    const float* __restrict__ inv_temp,
    float* __restrict__ partial)
{
    // --- XCD-contiguous remap: 2080 = 8 XCDs x 260 contiguous tri-ids ---
    const int bid = (blockIdx.x & 7) * 260 + (blockIdx.x >> 3);
    // --- triangular index: bid -> (rb, cb), rb <= cb ---
    int rb = (int)((129.0f - sqrtf(129.0f * 129.0f - 8.0f * (float)bid)) * 0.5f);
    rb = rb < 0 ? 0 : (rb > 63 ? 63 : rb);
    while (rb > 0 && (rb * (129 - rb)) / 2 > bid) rb--;
    while (rb < 63 && ((rb + 1) * (129 - (rb + 1))) / 2 <= bid) rb++;
    const int cb = rb + (bid - (rb * (129 - rb)) / 2);

    // double-buffered: 2 x 128 rows x 64 B = 2 x 8 KB per matrix = 32 KB
    __shared__ unsigned char smA[2][8192];
    __shared__ unsigned char smB[2][8192];

    const int rowBase = rb * 128;
    const int colBase = cb * 128;

    const int tid  = threadIdx.x;
    const int w    = tid >> 6;
    const int lane = tid & 63;
    const int quad = lane >> 4;
    const int t    = lane & 15;
    const int wm   = w >> 1;
    const int wn   = w & 1;

    // staging roles: each glds covers 16 rows x 4 units(16B) = 1 KB
    const int lr = lane >> 2;   // 0..15 (row within group)
    const int su = lane & 3;    // 0..3  (16B unit within row)

    const unsigned char* Arow0 = X8 + (size_t)rowBase * D_DIM;
    const unsigned char* Brow0 = X8 + (size_t)colBase * D_DIM;

    v4f acc[4][4];
    #pragma unroll
    for (int a = 0; a < 4; a++)
        #pragma unroll
        for (int b2 = 0; b2 < 4; b2++)
            acc[a][b2] = v4f{0.0f, 0.0f, 0.0f, 0.0f};

    const int hb = (t >> 1) & 3;            // read-side swizzle key
    const int aBase = (wm * 64 + t) * 64;   // LDS row base (A), rows mi*16 apart
    const int bBase = (wn * 64 + t) * 64;

    // ---- prologue: stage tile 0 into buffer 0 ----
    #pragma unroll
    for (int j = 0; j < 2; j++) {
        const int g = w * 2 + j;            // row group 0..7 (16 rows)
        const int r = g * 16 + lr;
        const int gc = su ^ ((r >> 1) & 3); // XOR swizzle via global unit
        gload_lds16(Arow0 + (size_t)r * D_DIM + gc * 16, &smA[0][g * 1024]);
        gload_lds16(Brow0 + (size_t)r * D_DIM + gc * 16, &smB[0][g * 1024]);
    }
    __syncthreads();

    // ---- 8-tile double-buffered main loop (BK=64) ----
    #pragma unroll
    for (int p = 0; p < 8; p++) {
        const int cur = p & 1;
        const int nxt = cur ^ 1;

        // issue next-tile staging FIRST (hidden under this tile's MFMAs)
        if (p < 7) {
            const int kk = (p + 1) * 64;
            #pragma unroll
            for (int j = 0; j < 2; j++) {
                const int g = w * 2 + j;
                const int r = g * 16 + lr;
                const int gc = su ^ ((r >> 1) & 3);
                gload_lds16(Arow0 + (size_t)r * D_DIM + kk + gc * 16, &smA[nxt][g * 1024]);
                gload_lds16(Brow0 + (size_t)r * D_DIM + kk + gc * 16, &smB[nxt][g * 1024]);
            }
        }

        // compute current tile: 2 k-slices of 32 B
        #pragma unroll
        for (int s = 0; s < 2; s++) {
            // global unit ug = s*2 + (quad>>1); stored at pu = ug ^ ((row>>1)&3)
            const int pu = (s * 2 + (quad >> 1)) ^ hb;
            const int off = pu * 16 + (quad & 1) * 8;
            long aF[4], bF[4];
            #pragma unroll
            for (int mi = 0; mi < 4; mi++)
                aF[mi] = *(const long*)&smA[cur][aBase + mi * 1024 + off];
            #pragma unroll
            for (int ni = 0; ni < 4; ni++)
                bF[ni] = *(const long*)&smB[cur][bBase + ni * 1024 + off];
            #pragma unroll
            for (int mi = 0; mi < 4; mi++)
                #pragma unroll
                for (int ni = 0; ni < 4; ni++)
                    acc[mi][ni] = __builtin_amdgcn_mfma_f32_16x16x32_fp8_fp8(
                        aF[mi], bF[ni], acc[mi][ni], 0, 0, 0);
        }

        // one barrier per tile: drains stage(p+1) after the MFMAs and
        // protects buf[cur] before phase p+1 restages into it.
        __syncthreads();
    }

    // ---- Epilogue 1: row sums (temp_i), slice 2*cb+wn ----
    v4f itv[4];
    #pragma unroll
    for (int mi = 0; mi < 4; mi++)
        itv[mi] = *(const v4f*)&inv_temp[rowBase + wm * 64 + mi * 16 + quad * 4];

    float* prow = partial + (size_t)(cb * 2 + wn) * TWO_B;
    #pragma unroll
    for (int mi = 0; mi < 4; mi++) {
        #pragma unroll
        for (int r = 0; r < 4; r++) {
            const int i = rowBase + wm * 64 + mi * 16 + quad * 4 + r;
            const float it = itv[mi][r];
            float s = 0.0f;
            #pragma unroll
            for (int ni = 0; ni < 4; ni++) {
                const int j = colBase + wn * 64 + ni * 16 + t;
                const float v = fast_exp2(acc[mi][ni][r] * it);
                s += (i == j) ? 0.0f : v;
            }
            s += __shfl_xor(s, 1, 64);
            s += __shfl_xor(s, 2, 64);
            s += __shfl_xor(s, 4, 64);
            s += __shfl_xor(s, 8, 64);
            if (t == 0) prow[i] = s;
        }
    }

    // ---- Epilogue 2 (off-diag): col sums (temp_j), slice 2*rb+wm ----
    if (rb != cb) {
        float itj[4];
        float cs[4] = {0.0f, 0.0f, 0.0f, 0.0f};
        #pragma unroll
        for (int ni = 0; ni < 4; ni++)
            itj[ni] = inv_temp[colBase + wn * 64 + ni * 16 + t];
        #pragma unroll
        for (int mi = 0; mi < 4; mi++)
            #pragma unroll
            for (int r = 0; r < 4; r++)
                #pragma unroll
                for (int ni = 0; ni < 4; ni++)
                    cs[ni] += fast_exp2(acc[mi][ni][r] * itj[ni]);
        float* pcol = partial + (size_t)(rb * 2 + wm) * TWO_B;
        #pragma unroll
        for (int ni = 0; ni < 4; ni++) {
            cs[ni] += __shfl_xor(cs[ni], 16, 64);
            cs[ni] += __shfl_xor(cs[ni], 32, 64);
            if (quad == 0) pcol[colBase + wn * 64 + ni * 16 + t] = cs[ni];
        }
    }
}

// ---------------------------------------------------------------------------
// Kernel 3a: denom = sum of 128 slices; loss_i = log(denom) - pos; block sums
// ---------------------------------------------------------------------------
__global__ __launch_bounds__(256) void finish1(
    const float* __restrict__ partial, const float* __restrict__ pos,
    float* __restrict__ blockSums)
{
    const int i = blockIdx.x * 256 + threadIdx.x;
    float d = 0.0f;
    #pragma unroll 8
    for (int s = 0; s < 128; s++) d += partial[(size_t)s * TWO_B + i];
    float li = logf(d) - pos[i & (B_ROWS - 1)];
    #pragma unroll
    for (int m = 1; m < 64; m <<= 1) li += __shfl_xor(li, m, 64);
    __shared__ float red[4];
    const int w = threadIdx.x >> 6, lane = threadIdx.x & 63;
    if (lane == 0) red[w] = li;
    __syncthreads();
    if (threadIdx.x == 0) blockSums[blockIdx.x] = red[0] + red[1] + red[2] + red[3];
}

__global__ void finish2(const float* __restrict__ blockSums, float* __restrict__ out)
{
    const int lane = threadIdx.x;
    float v = (lane < 32) ? blockSums[lane] : 0.0f;
    #pragma unroll
    for (int m = 1; m < 64; m <<= 1) v += __shfl_xor(v, m, 64);
    if (lane == 0) out[0] = v * (1.0f / 8192.0f);
}

// ---------------------------------------------------------------------------
extern "C" void kernel_launch(void* const* d_in, const int* in_sizes, int n_in,
                              void* d_out, int out_size, void* d_ws, size_t ws_size,
                              hipStream_t stream) {
    const float* emb1 = (const float*)d_in[0];
    const float* emb2 = (const float*)d_in[1];
    const float* att  = (const float*)d_in[2];
    float* out = (float*)d_out;

    char* ws = (char*)d_ws;
    // layout: X8 fp8 [8192*512] = 4,194,304 B
    //         inv_temp f32 [8192]      -> +32,768
    //         pos f32 [4096]           -> +16,384
    //         partial f32 [128*8192]   -> +4,194,304
    //         blockSums f32 [32]       -> +128
    unsigned short* X8 = (unsigned short*)ws;
    float* inv_temp    = (float*)(ws + 4194304);
    float* pos         = (float*)(ws + 4194304 + 32768);
    float* partial     = (float*)(ws + 4194304 + 32768 + 16384);
    float* blockSums   = (float*)(ws + 4194304 + 32768 + 16384 + 4194304);

    prep_kernel<<<B_ROWS, 256, 0, stream>>>(emb1, emb2, att, X8, inv_temp, pos);
    gram_kernel<<<2080, 256, 0, stream>>>((const unsigned char*)X8, inv_temp, partial);
    finish1<<<TWO_B / 256, 256, 0, stream>>>(partial, pos, blockSums);
    finish2<<<1, 64, 0, stream>>>(blockSums, out);
}